// Round 3
// baseline (345.339 us; speedup 1.0000x reference)
//
#include <hip/hip_runtime.h>

typedef unsigned short ushort_t;
typedef short v8s __attribute__((ext_vector_type(8)));   // 8 bf16 (4 VGPRs)
typedef float v4f __attribute__((ext_vector_type(4)));   // MFMA acc

#define BATCH    65536
#define UNITS    256
#define M_TILE   64
#define KSTEPS   16
#define BCHUNK   10240      // shorts per packed-K chunk: 256 cols * (32k + 8 pad)
#define T_STRIDE 264        // shorts per LDS tile row (528 B, 16B-aligned, 2-way banks)
#define LDS_HB   0
#define LDS_GT   33792
#define LDS_SC   67584
#define LDS_TOT  69376

__device__ __forceinline__ float b2f(ushort_t u) {
    union { unsigned int i; float f; } v; v.i = ((unsigned int)u) << 16; return v.f;
}
__device__ __forceinline__ ushort_t f2b(float f) {
    union { float f; unsigned int i; } v; v.f = f;
    unsigned int r = (v.i + 0x7fffu + ((v.i >> 16) & 1u)) >> 16;   // RNE
    return (ushort_t)r;
}

// ---- weight pre-pack: fp32 W[512][256] -> bf16 per-chunk [n][kl] -----------
// chunk c = k>>5 holds cols n=0..255, each 32 k-values + 8 pad (16B-aligned)
__global__ void pack_w(const float* __restrict__ w_in,
                       const float* __restrict__ w_rec,
                       ushort_t* __restrict__ Wp) {
    int gid = blockIdx.x * 256 + threadIdx.x;      // 0..131071
    int k = gid >> 8, n = gid & 255;
    float v = (k < 256) ? w_in[k * 256 + n] : w_rec[(k - 256) * 256 + n];
    Wp[(size_t)(k >> 5) * BCHUNK + n * 40 + (k & 31)] = f2b(v);
}

// ---- fused cell ------------------------------------------------------------
__global__ __launch_bounds__(256, 2)
void fused_cell(const float* __restrict__ inputs,
                const float* __restrict__ prev_h,
                const float* __restrict__ prev_G,
                const float* __restrict__ prev_phase,
                const ushort_t* __restrict__ Wp,
                const float* __restrict__ bias,
                float* __restrict__ out) {
    __shared__ __align__(16) char smem[LDS_TOT];
    short* Hb     = (short*)(smem + LDS_HB);      // 64 x 264 bf16 prev_h (orig order)
    short* Gt     = (short*)(smem + LDS_GT);      // 64 x 264 bf16 new_G
    float* r_mean = (float*)(smem + LDS_SC);
    float* r_rstd = r_mean + 64;
    float* r_comb = r_rstd + 64;
    float* bias_f = r_comb + 64;

    const int tid  = threadIdx.x;
    const int l    = tid & 63;
    const int w    = tid >> 6;
    const int row0 = blockIdx.x * M_TILE;

    float* outH = out;
    float* outG = out + (size_t)BATCH * UNITS;
    float* outP = out + (size_t)2 * BATCH * UNITS;

    bias_f[tid] = bias[tid];

    // ---- phase 1: new_G = 0.9*prev_G + 0.1*roll(prev_h), stats, oscillator
    for (int rr = 0; rr < 16; ++rr) {
        int lr = w * 16 + rr;
        int gr = row0 + lr;
        int c0 = l * 4;
        int pc = (c0 + 128) & 255;        // raw[:,c] = prev_h[:,(c+128)&255]
        float4 hp = *(const float4*)(prev_h + (size_t)gr * UNITS + pc);
        float4 gp = *(const float4*)(prev_G + (size_t)gr * UNITS + c0);
        float4 ng;
        ng.x = 0.9f * gp.x + 0.1f * hp.x;
        ng.y = 0.9f * gp.y + 0.1f * hp.y;
        ng.z = 0.9f * gp.z + 0.1f * hp.z;
        ng.w = 0.9f * gp.w + 0.1f * hp.w;
        float s1 = ng.x + ng.y + ng.z + ng.w;
        float s2 = ng.x*ng.x + ng.y*ng.y + ng.z*ng.z + ng.w*ng.w;
        float sh = hp.x + hp.y + hp.z + hp.w;
        *(float4*)(outG + (size_t)gr * UNITS + c0) = ng;          // output 1 (fp32)
        ushort4 gq; gq.x = f2b(ng.x); gq.y = f2b(ng.y); gq.z = f2b(ng.z); gq.w = f2b(ng.w);
        *(ushort4*)(Gt + lr * T_STRIDE + c0) = gq;                // epilogue copy
        ushort4 hq; hq.x = f2b(hp.x); hq.y = f2b(hp.y); hq.z = f2b(hp.z); hq.w = f2b(hp.w);
        *(ushort4*)(Hb + lr * T_STRIDE + pc) = hq;                // orig-order bf16 prev_h
        #pragma unroll
        for (int off = 32; off > 0; off >>= 1) {
            s1 += __shfl_xor(s1, off, 64);
            s2 += __shfl_xor(s2, off, 64);
            sh += __shfl_xor(sh, off, 64);
        }
        if (l == 0) {
            float mean = s1 * (1.f / 256.f);
            float var  = s2 * (1.f / 256.f) - mean * mean;         // population var
            float rstd = 1.f / (sqrtf(fmaxf(var, 0.f)) + 1e-6f);
            float np   = prev_phase[gr] + 0.2513274122871834591f;  // 2*pi/25
            outP[gr] = np;                                          // output 2 (fp32)
            float comb = sinf(np) + 0.05f * (sh * (1.f / 256.f) - 0.1f);
            r_mean[lr] = mean; r_rstd[lr] = rstd; r_comb[lr] = comb;
        }
    }

    __syncthreads();   // Hb + Gt + scalars visible

    // ---- phase 2: GEMM z = [inputs|prev_h] @ [w_in;w_rec]  (bf16 MFMA)
    // 16x16x32: A[m=lane&15][k=q*8+j]; B[k=q*8+j][n=lane&15]; C: col=lane&15,row=q*4+reg
    const int n16 = l & 15;
    const int q   = l >> 4;
    v4f acc[16];
    const v4f z4 = {0.f, 0.f, 0.f, 0.f};
    #pragma unroll
    for (int t = 0; t < 16; ++t) acc[t] = z4;

    const int arow = w * 16 + n16;
    const float* ainp = inputs + (size_t)(row0 + arow) * UNITS + q * 8;
    const short* hbp  = Hb + arow * T_STRIDE + q * 8;
    const short* bp   = (const short*)Wp + n16 * 40 + q * 8;

    #pragma unroll 2
    for (int s = 0; s < KSTEPS; ++s) {
        v8s a;
        if (s < 8) {
            float4 f0 = *(const float4*)(ainp + s * 32);
            float4 f1 = *(const float4*)(ainp + s * 32 + 4);
            a[0] = (short)f2b(f0.x); a[1] = (short)f2b(f0.y);
            a[2] = (short)f2b(f0.z); a[3] = (short)f2b(f0.w);
            a[4] = (short)f2b(f1.x); a[5] = (short)f2b(f1.y);
            a[6] = (short)f2b(f1.z); a[7] = (short)f2b(f1.w);
        } else {
            a = *(const v8s*)(hbp + (s - 8) * 32);
        }
        const short* bs = bp + s * BCHUNK;
        #pragma unroll
        for (int t = 0; t < 16; ++t) {
            v8s b = *(const v8s*)(bs + t * 640);   // col = t*16+n16, k = q*8+j
            acc[t] = __builtin_amdgcn_mfma_f32_16x16x32_bf16(a, b, acc[t], 0, 0, 0);
        }
    }

    // ---- epilogue: field_effect * (dot+bias) -> elu -> inertia -> clip
    #pragma unroll
    for (int t = 0; t < 16; ++t) {
        int c = t * 16 + n16;
        float bz = bias_f[c];
        #pragma unroll
        for (int r = 0; r < 4; ++r) {
            int lr = w * 16 + q * 4 + r;
            int gr = row0 + lr;
            float gval = b2f((ushort_t)Gt[lr * T_STRIDE + c]);
            float gn = (gval - r_mean[lr]) * r_rstd[lr];
            float e2 = __expf(2.f * gn);                       // tanh via exp
            float th = 1.f - 2.f / (e2 + 1.f);
            float field = 1.f + 0.5f * r_comb[lr] * th;
            float z = (acc[t][r] + bz) * field;
            float el = (z > 0.f) ? z : (__expf(z) - 1.f);
            float h = 0.9f * b2f((ushort_t)Hb[lr * T_STRIDE + c]) + 0.1f * el;
            h = fminf(fmaxf(h, -20.f), 20.f);
            outH[(size_t)gr * UNITS + c] = h;                  // output 0 (fp32)
        }
    }
}

extern "C" void kernel_launch(void* const* d_in, const int* in_sizes, int n_in,
                              void* d_out, int out_size, void* d_ws, size_t ws_size,
                              hipStream_t stream) {
    const float* inputs     = (const float*)d_in[0];
    const float* prev_h     = (const float*)d_in[1];
    const float* prev_G     = (const float*)d_in[2];
    const float* prev_phase = (const float*)d_in[3];
    const float* w_in       = (const float*)d_in[4];
    const float* w_rec      = (const float*)d_in[5];
    const float* bias       = (const float*)d_in[6];
    float* out    = (float*)d_out;
    ushort_t* Wp  = (ushort_t*)d_ws;       // 327,680 B packed bf16 weights

    pack_w<<<512, 256, 0, stream>>>(w_in, w_rec, Wp);
    fused_cell<<<BATCH / M_TILE, 256, 0, stream>>>(inputs, prev_h, prev_G,
                                                   prev_phase, Wp, bias, out);
}